// Round 1
// baseline (941.675 us; speedup 1.0000x reference)
//
#include <hip/hip_runtime.h>
#include <cstddef>
#include <cstdint>

#define NN   8192
#define FF   256
#define RESH 512
#define REPH 256
#define EMBD 128
#define EE   262144
#define GAMMA_ 0.1f

// ---------------- CSR construction ----------------

__global__ void count_kernel(const int* __restrict__ ei, int* __restrict__ cnt_src,
                             int* __restrict__ cnt_dst) {
  int e = blockIdx.x * blockDim.x + threadIdx.x;
  if (e < EE) {
    atomicAdd(&cnt_src[ei[e]], 1);
    atomicAdd(&cnt_dst[ei[EE + e]], 1);
  }
}

// one block per array; exclusive scan of N=8192 ints with 1024 threads
__global__ void scan_kernel(const int* __restrict__ cnt_src, const int* __restrict__ cnt_dst,
                            int* __restrict__ off_src, int* __restrict__ off_dst) {
  const int* cnt = blockIdx.x ? cnt_dst : cnt_src;
  int* off = blockIdx.x ? off_dst : off_src;
  __shared__ int sm[1024];
  int carry = 0;
  for (int ch = 0; ch < NN / 1024; ++ch) {
    int idx = ch * 1024 + threadIdx.x;
    int v = cnt[idx];
    int x = v;
    sm[threadIdx.x] = x;
    __syncthreads();
    for (int ofs = 1; ofs < 1024; ofs <<= 1) {
      int y = (threadIdx.x >= ofs) ? sm[threadIdx.x - ofs] : 0;
      __syncthreads();
      x += y;
      sm[threadIdx.x] = x;
      __syncthreads();
    }
    off[idx] = x - v + carry;
    carry += sm[1023];
    __syncthreads();
  }
  if (threadIdx.x == 0) off[NN] = carry;
}

__global__ void fill_kernel(const int* __restrict__ ei, const int* __restrict__ off_src,
                            const int* __restrict__ off_dst, int* __restrict__ cur_src,
                            int* __restrict__ cur_dst, int* __restrict__ adj_src,
                            int* __restrict__ adj_dst) {
  int e = blockIdx.x * blockDim.x + threadIdx.x;
  if (e < EE) {
    int s = ei[e], d = ei[EE + e];
    int ps = atomicAdd(&cur_src[s], 1);
    adj_src[off_src[s] + ps] = d;
    int pd = atomicAdd(&cur_dst[d], 1);
    adj_dst[off_dst[d] + pd] = s;
  }
}

__global__ void dinv_kernel(const int* __restrict__ cnt_dst, float* __restrict__ dinv) {
  int n = blockIdx.x * blockDim.x + threadIdx.x;
  if (n < NN) dinv[n] = rsqrtf((float)cnt_dst[n] + 1.0f);
}

// ---------------- sparse A @ res_W1 (+bias, relu) ----------------
// row i = sum over out-edges (i->d) of res_W1[d,:]
__global__ __launch_bounds__(256) void s1_kernel(const float* __restrict__ W1,
    const float* __restrict__ b1, const int* __restrict__ off_src,
    const int* __restrict__ adj_src, float* __restrict__ S1) {
  int i = blockIdx.x, t = threadIdx.x;
  int beg = off_src[i], end = off_src[i + 1];
  float a0 = 0.f, a1 = 0.f;
  for (int k = beg; k < end; ++k) {
    int d = adj_src[k];
    const float* row = W1 + (size_t)d * RESH;
    a0 += row[t];
    a1 += row[t + 256];
  }
  S1[(size_t)i * RESH + t]       = fmaxf(a0 + b1[t], 0.f);
  S1[(size_t)i * RESH + t + 256] = fmaxf(a1 + b1[t + 256], 0.f);
}

// ---------------- GCN aggregations ----------------
// layer0: no norm, out = relu(sum_{e:s->d} h[s] + b)
__global__ __launch_bounds__(256) void agg0_kernel(const float* __restrict__ h,
    const float* __restrict__ b, const int* __restrict__ off_dst,
    const int* __restrict__ adj_dst, float* __restrict__ out) {
  int d = blockIdx.x, t = threadIdx.x;
  int beg = off_dst[d], end = off_dst[d + 1];
  float acc = 0.f;
  for (int k = beg; k < end; ++k) {
    int s = adj_dst[k];
    acc += h[(size_t)s * REPH + t];
  }
  out[(size_t)d * REPH + t] = fmaxf(acc + b[t], 0.f);
}

// normalized: out = relu( dinv[d]*sum h[s]*dinv[s] + h[d]*dinv[d]^2 + b )
__global__ void aggn_kernel(const float* __restrict__ h, const float* __restrict__ b,
    const float* __restrict__ dinv, const int* __restrict__ off_dst,
    const int* __restrict__ adj_dst, float* __restrict__ out, int C) {
  int d = blockIdx.x, t = threadIdx.x;  // blockDim.x == C
  int beg = off_dst[d], end = off_dst[d + 1];
  float acc = 0.f;
  for (int k = beg; k < end; ++k) {
    int s = adj_dst[k];
    acc += h[(size_t)s * C + t] * dinv[s];
  }
  float dd = dinv[d];
  float v = acc * dd + h[(size_t)d * C + t] * dd * dd + b[t];
  out[(size_t)d * C + t] = fmaxf(v, 0.f);
}

// ---------------- elementwise modulation: out = h * exp(-gamma*r) ----------------
__global__ void mod_kernel(const float* __restrict__ h, const float* __restrict__ r,
                           float* __restrict__ out, int n) {
  int i = blockIdx.x * blockDim.x + threadIdx.x;
  if (i < n) out[i] = h[i] * expf(-GAMMA_ * r[i]);
}

// ---------------- generic fp32 GEMM: C = [relu](A@B + bias) ----------------
// BM=BN=64, BK=16, 256 threads, 4x4 microtile. M%64==0, Nc%64==0, K%16==0.
__global__ __launch_bounds__(256) void gemm64(const float* __restrict__ A,
    const float* __restrict__ B, const float* __restrict__ bias, float* __restrict__ C,
    int M, int K, int Nc, int doRelu) {
  __shared__ float As[16][68];
  __shared__ float Bs[16][68];
  int t = threadIdx.x;
  int tx = t & 15, ty = t >> 4;
  int bm = blockIdx.y * 64, bn = blockIdx.x * 64;
  float acc[4][4] = {};
  for (int k0 = 0; k0 < K; k0 += 16) {
#pragma unroll
    for (int i = 0; i < 4; ++i) {
      int lin = t + i * 256;
      int r = lin >> 4, c = lin & 15;
      As[c][r] = A[(size_t)(bm + r) * K + k0 + c];
    }
#pragma unroll
    for (int i = 0; i < 4; ++i) {
      int lin = t + i * 256;
      int r = lin >> 6, c = lin & 63;
      Bs[r][c] = B[(size_t)(k0 + r) * Nc + bn + c];
    }
    __syncthreads();
#pragma unroll
    for (int k = 0; k < 16; ++k) {
      float a[4], b[4];
#pragma unroll
      for (int i = 0; i < 4; ++i) a[i] = As[k][ty * 4 + i];
#pragma unroll
      for (int j = 0; j < 4; ++j) b[j] = Bs[k][tx * 4 + j];
#pragma unroll
      for (int i = 0; i < 4; ++i)
#pragma unroll
        for (int j = 0; j < 4; ++j) acc[i][j] += a[i] * b[j];
    }
    __syncthreads();
  }
#pragma unroll
  for (int i = 0; i < 4; ++i) {
    size_t r = (size_t)(bm + ty * 4 + i);
    int c0 = bn + tx * 4;
    float4 v;
    v.x = acc[i][0]; v.y = acc[i][1]; v.z = acc[i][2]; v.w = acc[i][3];
    if (bias) {
      v.x += bias[c0 + 0]; v.y += bias[c0 + 1]; v.z += bias[c0 + 2]; v.w += bias[c0 + 3];
    }
    if (doRelu) {
      v.x = fmaxf(v.x, 0.f); v.y = fmaxf(v.y, 0.f); v.z = fmaxf(v.z, 0.f); v.w = fmaxf(v.w, 0.f);
    }
    *(float4*)(&C[r * Nc + c0]) = v;
  }
}

// ---------------- A_hat = H @ H^T, H [N, EMBD] ----------------
__global__ __launch_bounds__(256) void ahat64(const float* __restrict__ H,
                                              float* __restrict__ C) {
  __shared__ float As[16][68];
  __shared__ float Bs[16][68];
  int t = threadIdx.x;
  int tx = t & 15, ty = t >> 4;
  int bi = blockIdx.y * 64, bj = blockIdx.x * 64;
  float acc[4][4] = {};
  for (int k0 = 0; k0 < EMBD; k0 += 16) {
#pragma unroll
    for (int i = 0; i < 4; ++i) {
      int lin = t + i * 256;
      int r = lin >> 4, c = lin & 15;
      As[c][r] = H[(size_t)(bi + r) * EMBD + k0 + c];
      Bs[c][r] = H[(size_t)(bj + r) * EMBD + k0 + c];
    }
    __syncthreads();
#pragma unroll
    for (int k = 0; k < 16; ++k) {
      float a[4], b[4];
#pragma unroll
      for (int i = 0; i < 4; ++i) a[i] = As[k][ty * 4 + i];
#pragma unroll
      for (int j = 0; j < 4; ++j) b[j] = Bs[k][tx * 4 + j];
#pragma unroll
      for (int i = 0; i < 4; ++i)
#pragma unroll
        for (int j = 0; j < 4; ++j) acc[i][j] += a[i] * b[j];
    }
    __syncthreads();
  }
#pragma unroll
  for (int i = 0; i < 4; ++i) {
    size_t r = (size_t)(bi + ty * 4 + i);
    float4 v;
    v.x = acc[i][0]; v.y = acc[i][1]; v.z = acc[i][2]; v.w = acc[i][3];
    *(float4*)(&C[r * NN + bj + tx * 4]) = v;
  }
}

// ---------------- launch ----------------

extern "C" void kernel_launch(void* const* d_in, const int* in_sizes, int n_in,
                              void* d_out, int out_size, void* d_ws, size_t ws_size,
                              hipStream_t stream) {
  const float* x      = (const float*)d_in[0];
  const int*   ei     = (const int*)d_in[1];
  const float* res_W1 = (const float*)d_in[2];
  const float* res_b1 = (const float*)d_in[3];
  const float* res_W2 = (const float*)d_in[4];
  const float* res_b2 = (const float*)d_in[5];
  const float* fc_W1  = (const float*)d_in[6];
  const float* fc_b1  = (const float*)d_in[7];
  const float* fc_W2  = (const float*)d_in[8];
  const float* fc_b2  = (const float*)d_in[9];
  const float* g_W0   = (const float*)d_in[10];
  const float* g_b0   = (const float*)d_in[11];
  const float* g_W1   = (const float*)d_in[12];
  const float* g_b1   = (const float*)d_in[13];
  const float* g_W2   = (const float*)d_in[14];
  const float* g_b2   = (const float*)d_in[15];
  const float* dec_W1 = (const float*)d_in[16];
  const float* dec_b1 = (const float*)d_in[17];
  const float* dec_W2 = (const float*)d_in[18];
  const float* dec_b2 = (const float*)d_in[19];

  float* out   = (float*)d_out;
  float* X_hat = out;                               // [N,F]
  float* A_hat = out + (size_t)NN * FF;             // [N,N]
  float* R     = A_hat + (size_t)NN * NN;           // [N,F]

  char* ws = (char*)d_ws;
  size_t o = 0;
  auto alloc = [&](size_t bytes) -> void* {
    void* p = ws + o;
    o += (bytes + 1023) & ~(size_t)1023;
    return p;
  };
  int* cnt_src = (int*)alloc(NN * 4);        // these four are contiguous (32KB each)
  int* cnt_dst = (int*)alloc(NN * 4);
  int* cur_src = (int*)alloc(NN * 4);
  int* cur_dst = (int*)alloc(NN * 4);
  int* off_src = (int*)alloc((NN + 1) * 4);
  int* off_dst = (int*)alloc((NN + 1) * 4);
  int* adj_src = (int*)alloc((size_t)EE * 4);
  int* adj_dst = (int*)alloc((size_t)EE * 4);
  float* dinv  = (float*)alloc(NN * 4);
  float* S1    = (float*)alloc((size_t)NN * RESH * 4);
  float* B1    = (float*)alloc((size_t)NN * REPH * 4);
  float* B2    = (float*)alloc((size_t)NN * REPH * 4);
  float* B3    = (float*)alloc((size_t)NN * REPH * 4);
  float* B4    = (float*)alloc((size_t)NN * REPH * 4);

  // zero the four contiguous counter arrays in one shot
  hipMemsetAsync(cnt_src, 0, (size_t)NN * 4 * 4, stream);

  count_kernel<<<EE / 256, 256, 0, stream>>>(ei, cnt_src, cnt_dst);
  scan_kernel<<<2, 1024, 0, stream>>>(cnt_src, cnt_dst, off_src, off_dst);
  fill_kernel<<<EE / 256, 256, 0, stream>>>(ei, off_src, off_dst, cur_src, cur_dst,
                                            adj_src, adj_dst);
  dinv_kernel<<<NN / 256, 256, 0, stream>>>(cnt_dst, dinv);

  // S1 = relu(A @ res_W1 + res_b1)   (sparse gather)
  s1_kernel<<<NN, 256, 0, stream>>>(res_W1, res_b1, off_src, adj_src, S1);
  // R = relu(S1 @ res_W2 + res_b2)
  gemm64<<<dim3(FF / 64, NN / 64), 256, 0, stream>>>(S1, res_W2, res_b2, R, NN, RESH, FF, 1);
  // B1 = x @ g_W0
  gemm64<<<dim3(REPH / 64, NN / 64), 256, 0, stream>>>(x, g_W0, nullptr, B1, NN, FF, REPH, 0);
  // B2 = relu(agg_nonorm(B1) + g_b0)
  agg0_kernel<<<NN, REPH, 0, stream>>>(B1, g_b0, off_dst, adj_dst, B2);
  // B3 = R_l = relu(R @ fc_W1 + fc_b1)
  gemm64<<<dim3(REPH / 64, NN / 64), 256, 0, stream>>>(R, fc_W1, fc_b1, B3, NN, FF, REPH, 1);
  // B1 = B2 * exp(-gamma*B3)
  mod_kernel<<<(NN * REPH) / 256, 256, 0, stream>>>(B2, B3, B1, NN * REPH);
  // B2 = B1 @ g_W1
  gemm64<<<dim3(REPH / 64, NN / 64), 256, 0, stream>>>(B1, g_W1, nullptr, B2, NN, REPH, REPH, 0);
  // B1 = relu(agg_norm(B2) + g_b1)
  aggn_kernel<<<NN, REPH, 0, stream>>>(B2, g_b1, dinv, off_dst, adj_dst, B1, REPH);
  // B4 = R_l2 = relu(B3 @ fc_W2 + fc_b2)
  gemm64<<<dim3(REPH / 64, NN / 64), 256, 0, stream>>>(B3, fc_W2, fc_b2, B4, NN, REPH, REPH, 1);
  // B2 = B1 * exp(-gamma*B4)
  mod_kernel<<<(NN * REPH) / 256, 256, 0, stream>>>(B1, B4, B2, NN * REPH);
  // B3 = B2 @ g_W2   [N, EMBD]
  gemm64<<<dim3(EMBD / 64, NN / 64), 256, 0, stream>>>(B2, g_W2, nullptr, B3, NN, REPH, EMBD, 0);
  // B4 = H = relu(agg_norm(B3) + g_b2)  [N, EMBD]
  aggn_kernel<<<NN, EMBD, 0, stream>>>(B3, g_b2, dinv, off_dst, adj_dst, B4, EMBD);
  // B1 = relu(B4 @ dec_W1 + dec_b1)
  gemm64<<<dim3(REPH / 64, NN / 64), 256, 0, stream>>>(B4, dec_W1, dec_b1, B1, NN, EMBD, REPH, 1);
  // X_hat = relu(B1 @ dec_W2 + dec_b2)
  gemm64<<<dim3(FF / 64, NN / 64), 256, 0, stream>>>(B1, dec_W2, dec_b2, X_hat, NN, REPH, FF, 1);
  // A_hat = B4 @ B4^T
  ahat64<<<dim3(NN / 64, NN / 64), 256, 0, stream>>>(B4, A_hat);
}

// Round 2
// 881.257 us; speedup vs baseline: 1.0686x; 1.0686x over previous
//
#include <hip/hip_runtime.h>
#include <cstddef>
#include <cstdint>

#define NN   8192
#define FF   256
#define RESH 512
#define REPH 256
#define EMBD 128
#define EE   262144
#define GAMMA_ 0.1f

typedef __attribute__((ext_vector_type(8))) short bf16x8;
typedef __attribute__((ext_vector_type(4))) float f32x4;

// split fp32 -> hi/lo bf16 (RTNE both): x ~= hi + lo with rel err ~2^-17
__device__ inline void f2hilo(float x, short& h, short& l) {
  unsigned u = __float_as_uint(x);
  unsigned r = u + 0x7FFFu + ((u >> 16) & 1u);
  h = (short)(r >> 16);
  float hf = __uint_as_float(r & 0xFFFF0000u);
  float lf = x - hf;
  unsigned u2 = __float_as_uint(lf);
  unsigned r2 = u2 + 0x7FFFu + ((u2 >> 16) & 1u);
  l = (short)(r2 >> 16);
}

// ---------------- CSR construction ----------------

__global__ void count_kernel(const int* __restrict__ ei, int* __restrict__ cnt_src,
                             int* __restrict__ cnt_dst) {
  int e = blockIdx.x * blockDim.x + threadIdx.x;
  if (e < EE) {
    atomicAdd(&cnt_src[ei[e]], 1);
    atomicAdd(&cnt_dst[ei[EE + e]], 1);
  }
}

__global__ void scan_kernel(const int* __restrict__ cnt_src, const int* __restrict__ cnt_dst,
                            int* __restrict__ off_src, int* __restrict__ off_dst) {
  const int* cnt = blockIdx.x ? cnt_dst : cnt_src;
  int* off = blockIdx.x ? off_dst : off_src;
  __shared__ int sm[1024];
  int carry = 0;
  for (int ch = 0; ch < NN / 1024; ++ch) {
    int idx = ch * 1024 + threadIdx.x;
    int v = cnt[idx];
    int x = v;
    sm[threadIdx.x] = x;
    __syncthreads();
    for (int ofs = 1; ofs < 1024; ofs <<= 1) {
      int y = (threadIdx.x >= ofs) ? sm[threadIdx.x - ofs] : 0;
      __syncthreads();
      x += y;
      sm[threadIdx.x] = x;
      __syncthreads();
    }
    off[idx] = x - v + carry;
    carry += sm[1023];
    __syncthreads();
  }
  if (threadIdx.x == 0) off[NN] = carry;
}

__global__ void fill_kernel(const int* __restrict__ ei, const int* __restrict__ off_src,
                            const int* __restrict__ off_dst, int* __restrict__ cur_src,
                            int* __restrict__ cur_dst, int* __restrict__ adj_src,
                            int* __restrict__ adj_dst) {
  int e = blockIdx.x * blockDim.x + threadIdx.x;
  if (e < EE) {
    int s = ei[e], d = ei[EE + e];
    int ps = atomicAdd(&cur_src[s], 1);
    adj_src[off_src[s] + ps] = d;
    int pd = atomicAdd(&cur_dst[d], 1);
    adj_dst[off_dst[d] + pd] = s;
  }
}

__global__ void dinv_kernel(const int* __restrict__ cnt_dst, float* __restrict__ dinv) {
  int n = blockIdx.x * blockDim.x + threadIdx.x;
  if (n < NN) dinv[n] = rsqrtf((float)cnt_dst[n] + 1.0f);
}

// ---------------- sparse A @ res_W1 (+bias, relu) ----------------
__global__ __launch_bounds__(256) void s1_kernel(const float* __restrict__ W1,
    const float* __restrict__ b1, const int* __restrict__ off_src,
    const int* __restrict__ adj_src, float* __restrict__ S1) {
  int i = blockIdx.x, t = threadIdx.x;
  int beg = off_src[i], end = off_src[i + 1];
  float a0 = 0.f, a1 = 0.f;
#pragma unroll 4
  for (int k = beg; k < end; ++k) {
    int d = adj_src[k];
    const float* row = W1 + (size_t)d * RESH;
    a0 += row[t];
    a1 += row[t + 256];
  }
  S1[(size_t)i * RESH + t]       = fmaxf(a0 + b1[t], 0.f);
  S1[(size_t)i * RESH + t + 256] = fmaxf(a1 + b1[t + 256], 0.f);
}

// ---------------- GCN aggregations ----------------
__global__ __launch_bounds__(256) void agg0_kernel(const float* __restrict__ h,
    const float* __restrict__ b, const int* __restrict__ off_dst,
    const int* __restrict__ adj_dst, float* __restrict__ out) {
  int d = blockIdx.x, t = threadIdx.x;
  int beg = off_dst[d], end = off_dst[d + 1];
  float acc = 0.f;
#pragma unroll 4
  for (int k = beg; k < end; ++k) {
    int s = adj_dst[k];
    acc += h[(size_t)s * REPH + t];
  }
  out[(size_t)d * REPH + t] = fmaxf(acc + b[t], 0.f);
}

__global__ void aggn_kernel(const float* __restrict__ h, const float* __restrict__ b,
    const float* __restrict__ dinv, const int* __restrict__ off_dst,
    const int* __restrict__ adj_dst, float* __restrict__ out, int C) {
  int d = blockIdx.x, t = threadIdx.x;  // blockDim.x == C
  int beg = off_dst[d], end = off_dst[d + 1];
  float acc = 0.f;
#pragma unroll 4
  for (int k = beg; k < end; ++k) {
    int s = adj_dst[k];
    acc += h[(size_t)s * C + t] * dinv[s];
  }
  float dd = dinv[d];
  float v = acc * dd + h[(size_t)d * C + t] * dd * dd + b[t];
  out[(size_t)d * C + t] = fmaxf(v, 0.f);
}

// ---------------- weight prep: W [K][N] fp32 -> Wt hi/lo bf16 [N][K] ----------------
struct WDesc { const float* src; short* h; short* l; int K; int N; };
struct WTab { WDesc d[8]; };

__global__ void prep_w(WTab tab) {
  WDesc d = tab.d[blockIdx.y];
  int total = d.K * d.N;
  for (int i = blockIdx.x * 256 + threadIdx.x; i < total; i += 128 * 256) {
    int n = i / d.K, k = i - n * d.K;
    float x = d.src[(size_t)k * d.N + n];
    short hh, ll;
    f2hilo(x, hh, ll);
    d.h[i] = hh;
    d.l[i] = ll;
  }
}

// ---------------- H fp32 -> hi/lo bf16 ----------------
__global__ void conv_h(const float* __restrict__ Hf, short* __restrict__ Hh,
                       short* __restrict__ Hl) {
  int i = blockIdx.x * 256 + threadIdx.x;  // grid covers NN*EMBD exactly
  float x = Hf[i];
  short hh, ll;
  f2hilo(x, hh, ll);
  Hh[i] = hh;
  Hl[i] = ll;
}

// ---------------- split-bf16 MFMA GEMM ----------------
// C[M=8192][Nc] = [relu]( (A .* exp(-g*Rm)) @ W + bias ),  W given as Wt hi/lo [Nc][K] bf16.
// block = 256 thr (4 waves), each wave: 16 rows x 128 cols; grid = (Nc/128, M/64).
// No LDS, no barriers: fragments straight from global (weights L2-resident).
__global__ __launch_bounds__(256) void gemmW(const float* __restrict__ A,
    const float* __restrict__ Rm, const short* __restrict__ Wh,
    const short* __restrict__ Wl, const float* __restrict__ bias,
    float* __restrict__ C, int K, int Nc, int doRelu) {
  const int w = threadIdx.x >> 6, l = threadIdx.x & 63;
  const int lr = l & 15, lk = l >> 4;
  const int m0 = blockIdx.y * 64 + w * 16;
  const int n0 = blockIdx.x * 128;
  f32x4 acc[8] = {};
  const int nks = K >> 5;
  for (int ks = 0; ks < nks; ++ks) {
    const int k0 = (ks << 5) + (lk << 3);
    const float* ap = A + (size_t)(m0 + lr) * K + k0;
    float av[8];
    *(f32x4*)(av + 0) = *(const f32x4*)(ap + 0);
    *(f32x4*)(av + 4) = *(const f32x4*)(ap + 4);
    if (Rm) {
      const float* rp = Rm + (size_t)(m0 + lr) * K + k0;
      float rv[8];
      *(f32x4*)(rv + 0) = *(const f32x4*)(rp + 0);
      *(f32x4*)(rv + 4) = *(const f32x4*)(rp + 4);
#pragma unroll
      for (int j = 0; j < 8; ++j) av[j] *= expf(-GAMMA_ * rv[j]);
    }
    bf16x8 ah, al;
#pragma unroll
    for (int j = 0; j < 8; ++j) {
      short hh, ll;
      f2hilo(av[j], hh, ll);
      ah[j] = hh;
      al[j] = ll;
    }
#pragma unroll
    for (int cb = 0; cb < 8; ++cb) {
      size_t boff = (size_t)(n0 + (cb << 4) + lr) * K + k0;
      bf16x8 bh = *(const bf16x8*)(Wh + boff);
      bf16x8 bl = *(const bf16x8*)(Wl + boff);
      acc[cb] = __builtin_amdgcn_mfma_f32_16x16x32_bf16(ah, bh, acc[cb], 0, 0, 0);
      acc[cb] = __builtin_amdgcn_mfma_f32_16x16x32_bf16(al, bh, acc[cb], 0, 0, 0);
      acc[cb] = __builtin_amdgcn_mfma_f32_16x16x32_bf16(ah, bl, acc[cb], 0, 0, 0);
    }
  }
#pragma unroll
  for (int cb = 0; cb < 8; ++cb) {
    int col = n0 + (cb << 4) + lr;
    float bv = bias ? bias[col] : 0.f;
#pragma unroll
    for (int r = 0; r < 4; ++r) {
      int row = m0 + (lk << 2) + r;
      float v = acc[cb][r] + bv;
      if (doRelu) v = fmaxf(v, 0.f);
      C[(size_t)row * Nc + col] = v;
    }
  }
}

// ---------------- A_hat = H @ H^T via split-bf16 MFMA ----------------
// block = 256 thr (4 waves); tile 128x128 (wave: 32 rows x 128 cols); K = EMBD = 128.
__global__ __launch_bounds__(256) void ahat_mfma(const short* __restrict__ Hh,
    const short* __restrict__ Hl, float* __restrict__ C) {
  const int w = threadIdx.x >> 6, l = threadIdx.x & 63;
  const int lr = l & 15, lk = l >> 4;
  const int bi = blockIdx.y * 128 + w * 32;
  const int bj = blockIdx.x * 128;
  f32x4 acc[2][8] = {};
#pragma unroll
  for (int ks = 0; ks < 4; ++ks) {
    const int k0 = (ks << 5) + (lk << 3);
    bf16x8 ah[2], al[2];
#pragma unroll
    for (int rb = 0; rb < 2; ++rb) {
      size_t off = (size_t)(bi + (rb << 4) + lr) * EMBD + k0;
      ah[rb] = *(const bf16x8*)(Hh + off);
      al[rb] = *(const bf16x8*)(Hl + off);
    }
#pragma unroll
    for (int cb = 0; cb < 8; ++cb) {
      size_t off = (size_t)(bj + (cb << 4) + lr) * EMBD + k0;
      bf16x8 bh = *(const bf16x8*)(Hh + off);
      bf16x8 bl = *(const bf16x8*)(Hl + off);
#pragma unroll
      for (int rb = 0; rb < 2; ++rb) {
        acc[rb][cb] = __builtin_amdgcn_mfma_f32_16x16x32_bf16(ah[rb], bh, acc[rb][cb], 0, 0, 0);
        acc[rb][cb] = __builtin_amdgcn_mfma_f32_16x16x32_bf16(al[rb], bh, acc[rb][cb], 0, 0, 0);
        acc[rb][cb] = __builtin_amdgcn_mfma_f32_16x16x32_bf16(ah[rb], bl, acc[rb][cb], 0, 0, 0);
      }
    }
  }
#pragma unroll
  for (int rb = 0; rb < 2; ++rb)
#pragma unroll
    for (int cb = 0; cb < 8; ++cb) {
      int row = bi + (rb << 4) + (lk << 2);
      int col = bj + (cb << 4) + lr;
#pragma unroll
      for (int r = 0; r < 4; ++r)
        C[(size_t)(row + r) * NN + col] = acc[rb][cb][r];
    }
}

// ---------------- launch ----------------

extern "C" void kernel_launch(void* const* d_in, const int* in_sizes, int n_in,
                              void* d_out, int out_size, void* d_ws, size_t ws_size,
                              hipStream_t stream) {
  const float* x      = (const float*)d_in[0];
  const int*   ei     = (const int*)d_in[1];
  const float* res_W1 = (const float*)d_in[2];
  const float* res_b1 = (const float*)d_in[3];
  const float* res_W2 = (const float*)d_in[4];
  const float* res_b2 = (const float*)d_in[5];
  const float* fc_W1  = (const float*)d_in[6];
  const float* fc_b1  = (const float*)d_in[7];
  const float* fc_W2  = (const float*)d_in[8];
  const float* fc_b2  = (const float*)d_in[9];
  const float* g_W0   = (const float*)d_in[10];
  const float* g_b0   = (const float*)d_in[11];
  const float* g_W1   = (const float*)d_in[12];
  const float* g_b1   = (const float*)d_in[13];
  const float* g_W2   = (const float*)d_in[14];
  const float* g_b2   = (const float*)d_in[15];
  const float* dec_W1 = (const float*)d_in[16];
  const float* dec_b1 = (const float*)d_in[17];
  const float* dec_W2 = (const float*)d_in[18];
  const float* dec_b2 = (const float*)d_in[19];

  float* out   = (float*)d_out;
  float* X_hat = out;                               // [N,F]
  float* A_hat = out + (size_t)NN * FF;             // [N,N]
  float* R     = A_hat + (size_t)NN * NN;           // [N,F]

  char* ws = (char*)d_ws;
  size_t o = 0;
  auto alloc = [&](size_t bytes) -> void* {
    void* p = ws + o;
    o += (bytes + 1023) & ~(size_t)1023;
    return p;
  };
  int* cnt_src = (int*)alloc(NN * 4);   // 4 contiguous counter arrays (zeroed in one memset)
  int* cnt_dst = (int*)alloc(NN * 4);
  int* cur_src = (int*)alloc(NN * 4);
  int* cur_dst = (int*)alloc(NN * 4);
  int* off_src = (int*)alloc((NN + 1) * 4);
  int* off_dst = (int*)alloc((NN + 1) * 4);
  int* adj_src = (int*)alloc((size_t)EE * 4);
  int* adj_dst = (int*)alloc((size_t)EE * 4);
  float* dinv  = (float*)alloc(NN * 4);
  float* S1    = (float*)alloc((size_t)NN * RESH * 4);
  float* B1    = (float*)alloc((size_t)NN * REPH * 4);
  float* B2    = (float*)alloc((size_t)NN * REPH * 4);
  float* B3    = (float*)alloc((size_t)NN * REPH * 4);
  float* B4    = (float*)alloc((size_t)NN * REPH * 4);
  short* Wt_h  = (short*)alloc(524288 * 2);
  short* Wt_l  = (short*)alloc(524288 * 2);
  short* Hh    = (short*)alloc((size_t)NN * EMBD * 2);
  short* Hl    = (short*)alloc((size_t)NN * EMBD * 2);

  // Wt layout offsets (elements), all stored [N][K]:
  const int o_resW2 = 0;        // 512x256 -> [256][512]
  const int o_fcW1  = 131072;   // [256][256]
  const int o_fcW2  = 196608;
  const int o_gW0   = 262144;
  const int o_gW1   = 327680;
  const int o_gW2   = 393216;   // 256x128 -> [128][256]
  const int o_decW1 = 425984;   // 128x256 -> [256][128]
  const int o_decW2 = 458752;

  hipMemsetAsync(cnt_src, 0, (size_t)NN * 4 * 4, stream);

  count_kernel<<<EE / 256, 256, 0, stream>>>(ei, cnt_src, cnt_dst);
  scan_kernel<<<2, 1024, 0, stream>>>(cnt_src, cnt_dst, off_src, off_dst);
  fill_kernel<<<EE / 256, 256, 0, stream>>>(ei, off_src, off_dst, cur_src, cur_dst,
                                            adj_src, adj_dst);
  dinv_kernel<<<NN / 256, 256, 0, stream>>>(cnt_dst, dinv);

  WTab tab;
  tab.d[0] = {res_W2, Wt_h + o_resW2, Wt_l + o_resW2, RESH, FF};
  tab.d[1] = {fc_W1,  Wt_h + o_fcW1,  Wt_l + o_fcW1,  FF,   REPH};
  tab.d[2] = {fc_W2,  Wt_h + o_fcW2,  Wt_l + o_fcW2,  REPH, REPH};
  tab.d[3] = {g_W0,   Wt_h + o_gW0,   Wt_l + o_gW0,   FF,   REPH};
  tab.d[4] = {g_W1,   Wt_h + o_gW1,   Wt_l + o_gW1,   REPH, REPH};
  tab.d[5] = {g_W2,   Wt_h + o_gW2,   Wt_l + o_gW2,   REPH, EMBD};
  tab.d[6] = {dec_W1, Wt_h + o_decW1, Wt_l + o_decW1, EMBD, REPH};
  tab.d[7] = {dec_W2, Wt_h + o_decW2, Wt_l + o_decW2, REPH, FF};
  prep_w<<<dim3(128, 8), 256, 0, stream>>>(tab);

  // S1 = relu(A @ res_W1 + res_b1)   (sparse gather)
  s1_kernel<<<NN, 256, 0, stream>>>(res_W1, res_b1, off_src, adj_src, S1);
  // R = relu(S1 @ res_W2 + res_b2)
  gemmW<<<dim3(FF / 128, NN / 64), 256, 0, stream>>>(S1, nullptr, Wt_h + o_resW2,
      Wt_l + o_resW2, res_b2, R, RESH, FF, 1);
  // B1 = x @ g_W0 (bias/relu applied after aggregation)
  gemmW<<<dim3(REPH / 128, NN / 64), 256, 0, stream>>>(x, nullptr, Wt_h + o_gW0,
      Wt_l + o_gW0, nullptr, B1, FF, REPH, 0);
  // B2 = relu(agg_nonorm(B1) + g_b0)
  agg0_kernel<<<NN, REPH, 0, stream>>>(B1, g_b0, off_dst, adj_dst, B2);
  // B3 = R_l = relu(R @ fc_W1 + fc_b1)
  gemmW<<<dim3(REPH / 128, NN / 64), 256, 0, stream>>>(R, nullptr, Wt_h + o_fcW1,
      Wt_l + o_fcW1, fc_b1, B3, FF, REPH, 1);
  // B1 = (B2 .* exp(-g*B3)) @ g_W1   (mod fused)
  gemmW<<<dim3(REPH / 128, NN / 64), 256, 0, stream>>>(B2, B3, Wt_h + o_gW1,
      Wt_l + o_gW1, nullptr, B1, REPH, REPH, 0);
  // B2 = relu(agg_norm(B1) + g_b1)
  aggn_kernel<<<NN, REPH, 0, stream>>>(B1, g_b1, dinv, off_dst, adj_dst, B2, REPH);
  // B4 = R_l2 = relu(B3 @ fc_W2 + fc_b2)
  gemmW<<<dim3(REPH / 128, NN / 64), 256, 0, stream>>>(B3, nullptr, Wt_h + o_fcW2,
      Wt_l + o_fcW2, fc_b2, B4, REPH, REPH, 1);
  // B3 = (B2 .* exp(-g*B4)) @ g_W2   [N, EMBD]
  gemmW<<<dim3(EMBD / 128, NN / 64), 256, 0, stream>>>(B2, B4, Wt_h + o_gW2,
      Wt_l + o_gW2, nullptr, B3, REPH, EMBD, 0);
  // B1 = H = relu(agg_norm(B3) + g_b2)  [N, EMBD]
  aggn_kernel<<<NN, EMBD, 0, stream>>>(B3, g_b2, dinv, off_dst, adj_dst, B1, EMBD);
  // Hh/Hl = split(H)
  conv_h<<<(NN * EMBD) / 256, 256, 0, stream>>>(B1, Hh, Hl);
  // B2 = relu(H @ dec_W1 + dec_b1)
  gemmW<<<dim3(REPH / 128, NN / 64), 256, 0, stream>>>(B1, nullptr, Wt_h + o_decW1,
      Wt_l + o_decW1, dec_b1, B2, EMBD, REPH, 1);
  // X_hat = relu(B2 @ dec_W2 + dec_b2)
  gemmW<<<dim3(FF / 128, NN / 64), 256, 0, stream>>>(B2, nullptr, Wt_h + o_decW2,
      Wt_l + o_decW2, dec_b2, X_hat, REPH, FF, 1);
  // A_hat = H @ H^T
  ahat_mfma<<<dim3(NN / 128, NN / 128), 256, 0, stream>>>(Hh, Hl, A_hat);
}

// Round 4
// 800.239 us; speedup vs baseline: 1.1767x; 1.1012x over previous
//
#include <hip/hip_runtime.h>
#include <cstddef>
#include <cstdint>
#include <math.h>

#define NN   8192
#define FF   256
#define RESH 512
#define REPH 256
#define EMBD 128
#define EE   262144
#define GAMMA_ 0.1f

typedef __attribute__((ext_vector_type(8))) short bf16x8;
typedef __attribute__((ext_vector_type(4))) float f32x4;
typedef __attribute__((ext_vector_type(4))) short s16x4;

// split fp32 -> hi/lo bf16 (RTNE both): x ~= hi + lo with rel err ~2^-17
__device__ inline void f2hilo(float x, short& h, short& l) {
  unsigned u = __float_as_uint(x);
  unsigned r = u + 0x7FFFu + ((u >> 16) & 1u);
  h = (short)(r >> 16);
  float hf = __uint_as_float(r & 0xFFFF0000u);
  float lf = x - hf;
  unsigned u2 = __float_as_uint(lf);
  unsigned r2 = u2 + 0x7FFFu + ((u2 >> 16) & 1u);
  l = (short)(r2 >> 16);
}

// ---------------- CSR construction ----------------

__global__ void count_kernel(const int* __restrict__ ei, int* __restrict__ cnt_src,
                             int* __restrict__ cnt_dst) {
  int e = blockIdx.x * blockDim.x + threadIdx.x;
  if (e < EE) {
    atomicAdd(&cnt_src[ei[e]], 1);
    atomicAdd(&cnt_dst[ei[EE + e]], 1);
  }
}

__global__ void scan_kernel(const int* __restrict__ cnt_src, const int* __restrict__ cnt_dst,
                            int* __restrict__ off_src, int* __restrict__ off_dst) {
  const int* cnt = blockIdx.x ? cnt_dst : cnt_src;
  int* off = blockIdx.x ? off_dst : off_src;
  __shared__ int sm[1024];
  int carry = 0;
  for (int ch = 0; ch < NN / 1024; ++ch) {
    int idx = ch * 1024 + threadIdx.x;
    int v = cnt[idx];
    int x = v;
    sm[threadIdx.x] = x;
    __syncthreads();
    for (int ofs = 1; ofs < 1024; ofs <<= 1) {
      int y = (threadIdx.x >= ofs) ? sm[threadIdx.x - ofs] : 0;
      __syncthreads();
      x += y;
      sm[threadIdx.x] = x;
      __syncthreads();
    }
    off[idx] = x - v + carry;
    carry += sm[1023];
    __syncthreads();
  }
  if (threadIdx.x == 0) off[NN] = carry;
}

__global__ void fill_kernel(const int* __restrict__ ei, const int* __restrict__ off_src,
                            const int* __restrict__ off_dst, int* __restrict__ cur_src,
                            int* __restrict__ cur_dst, int* __restrict__ adj_src,
                            int* __restrict__ adj_dst) {
  int e = blockIdx.x * blockDim.x + threadIdx.x;
  if (e < EE) {
    int s = ei[e], d = ei[EE + e];
    int ps = atomicAdd(&cur_src[s], 1);
    adj_src[off_src[s] + ps] = d;
    int pd = atomicAdd(&cur_dst[d], 1);
    adj_dst[off_dst[d] + pd] = s;
  }
}

__global__ void dinv_kernel(const int* __restrict__ cnt_dst, float* __restrict__ dinv) {
  int n = blockIdx.x * blockDim.x + threadIdx.x;
  if (n < NN) dinv[n] = rsqrtf((float)cnt_dst[n] + 1.0f);
}

// ---------------- sparse A @ res_W1, relu, split to hi/lo ----------------
__global__ __launch_bounds__(256) void s1_kernel(const float* __restrict__ W1,
    const float* __restrict__ b1, const int* __restrict__ off_src,
    const int* __restrict__ adj_src, short* __restrict__ S1h, short* __restrict__ S1l) {
  int i = blockIdx.x, t = threadIdx.x;
  int beg = off_src[i], end = off_src[i + 1];
  float a0 = 0.f, a1 = 0.f;
#pragma unroll 4
  for (int k = beg; k < end; ++k) {
    int d = adj_src[k];
    const float* row = W1 + (size_t)d * RESH;
    a0 += row[t];
    a1 += row[t + 256];
  }
  float v0 = fmaxf(a0 + b1[t], 0.f);
  float v1 = fmaxf(a1 + b1[t + 256], 0.f);
  short hh, ll;
  f2hilo(v0, hh, ll);
  S1h[(size_t)i * RESH + t] = hh;
  S1l[(size_t)i * RESH + t] = ll;
  f2hilo(v1, hh, ll);
  S1h[(size_t)i * RESH + t + 256] = hh;
  S1l[(size_t)i * RESH + t + 256] = ll;
}

// ---------------- GCN aggregations (fused bias/relu/mod/split epilogues) ----------------
__global__ __launch_bounds__(256) void agg0_fused(const float* __restrict__ h,
    const float* __restrict__ b, const float* __restrict__ mod,
    const int* __restrict__ off_dst, const int* __restrict__ adj_dst,
    short* __restrict__ oh, short* __restrict__ ol) {
  int d = blockIdx.x, t = threadIdx.x;
  int beg = off_dst[d], end = off_dst[d + 1];
  float acc = 0.f;
#pragma unroll 4
  for (int k = beg; k < end; ++k) {
    int s = adj_dst[k];
    acc += h[(size_t)s * REPH + t];
  }
  size_t o = (size_t)d * REPH + t;
  float v = fmaxf(acc + b[t], 0.f) * expf(-GAMMA_ * mod[o]);
  short hh, ll;
  f2hilo(v, hh, ll);
  oh[o] = hh;
  ol[o] = ll;
}

__global__ void aggn_fused(const float* __restrict__ h, const float* __restrict__ b,
    const float* __restrict__ dinv, const float* __restrict__ mod,
    const int* __restrict__ off_dst, const int* __restrict__ adj_dst,
    short* __restrict__ oh, short* __restrict__ ol, int C) {
  int d = blockIdx.x, t = threadIdx.x;  // blockDim.x == C
  int beg = off_dst[d], end = off_dst[d + 1];
  float acc = 0.f;
#pragma unroll 4
  for (int k = beg; k < end; ++k) {
    int s = adj_dst[k];
    acc += h[(size_t)s * C + t] * dinv[s];
  }
  float dd = dinv[d];
  size_t o = (size_t)d * C + t;
  float v = fmaxf(acc * dd + h[o] * dd * dd + b[t], 0.f);
  if (mod) v *= expf(-GAMMA_ * mod[o]);
  short hh, ll;
  f2hilo(v, hh, ll);
  oh[o] = hh;
  ol[o] = ll;
}

// ---------------- weight prep: W [K][N] fp32 -> hi/lo bf16 [N][K] ----------------
struct WDesc { const float* src; short* h; short* l; int K; int N; };
struct WTab { WDesc d[8]; };

__global__ void prep_w(WTab tab) {
  WDesc d = tab.d[blockIdx.y];
  int total = d.K * d.N;
  for (int i = blockIdx.x * 256 + threadIdx.x; i < total; i += 128 * 256) {
    int n = i / d.K, k = i - n * d.K;
    float x = d.src[(size_t)k * d.N + n];
    short hh, ll;
    f2hilo(x, hh, ll);
    d.h[i] = hh;
    d.l[i] = ll;
  }
}

// ---------------- fp32 -> hi/lo planes (vectorized), n % 1024 == 0 ----------------
__global__ void conv_split(const float* __restrict__ in, short* __restrict__ oh,
                           short* __restrict__ ol) {
  int i = (blockIdx.x * 256 + threadIdx.x) * 4;
  f32x4 v = *(const f32x4*)(in + i);
  s16x4 vh, vl;
#pragma unroll
  for (int j = 0; j < 4; ++j) {
    short hh, ll;
    f2hilo(v[j], hh, ll);
    vh[j] = hh;
    vl[j] = ll;
  }
  *(s16x4*)(oh + i) = vh;
  *(s16x4*)(ol + i) = vl;
}

// ---------------- split-bf16 MFMA GEMM, pre-split A and W planes ----------------
// C[M=8192][Nc] = [relu](A @ W + bias); A as [M][K] hi/lo, W as [Nc][K] hi/lo.
// 256 thr = 4 waves; wave: 16 rows x CB*16 cols. grid = (Nc/(CB*16), M/64).
template<int CB>
__global__ __launch_bounds__(256) void gemmS(const short* __restrict__ Ah,
    const short* __restrict__ Al, const short* __restrict__ Wh,
    const short* __restrict__ Wl, const float* __restrict__ bias, int doRelu,
    float* __restrict__ outF, short* __restrict__ outH, short* __restrict__ outL,
    int K, int Nc) {
  const int w = threadIdx.x >> 6, l = threadIdx.x & 63;
  const int lr = l & 15, lk = l >> 4;
  const int m0 = blockIdx.y * 64 + w * 16;
  const int n0 = blockIdx.x * (CB * 16);
  f32x4 acc[CB] = {};
  const int nks = K >> 5;
  for (int ks = 0; ks < nks; ++ks) {
    const int k0 = (ks << 5) + (lk << 3);
    size_t aoff = (size_t)(m0 + lr) * K + k0;
    bf16x8 ah = *(const bf16x8*)(Ah + aoff);
    bf16x8 al = *(const bf16x8*)(Al + aoff);
#pragma unroll
    for (int cb = 0; cb < CB; ++cb) {
      size_t boff = (size_t)(n0 + (cb << 4) + lr) * K + k0;
      bf16x8 bh = *(const bf16x8*)(Wh + boff);
      bf16x8 bl = *(const bf16x8*)(Wl + boff);
      acc[cb] = __builtin_amdgcn_mfma_f32_16x16x32_bf16(ah, bh, acc[cb], 0, 0, 0);
      acc[cb] = __builtin_amdgcn_mfma_f32_16x16x32_bf16(al, bh, acc[cb], 0, 0, 0);
      acc[cb] = __builtin_amdgcn_mfma_f32_16x16x32_bf16(ah, bl, acc[cb], 0, 0, 0);
    }
  }
#pragma unroll
  for (int cb = 0; cb < CB; ++cb) {
    int col = n0 + (cb << 4) + lr;
    float bv = bias ? bias[col] : 0.f;
#pragma unroll
    for (int r = 0; r < 4; ++r) {
      int row = m0 + (lk << 2) + r;
      float v = acc[cb][r] + bv;
      if (doRelu) v = fmaxf(v, 0.f);
      size_t off = (size_t)row * Nc + col;
      if (outF) outF[off] = v;
      if (outH) {
        short hh, ll;
        f2hilo(v, hh, ll);
        outH[off] = hh;
        outL[off] = ll;
      }
    }
  }
}

// ---------------- A_hat = H @ H^T (symmetric: upper-tri tiles + LDS-transposed mirror) ----
__global__ __launch_bounds__(256) void ahat_sym(const short* __restrict__ Hh,
    const short* __restrict__ Hl, float* __restrict__ C) {
  __shared__ float sm[128][129];
  int z = blockIdx.x;
  int b = (int)((sqrtf(8.f * (float)z + 1.f) - 1.f) * 0.5f);
  while ((b + 1) * (b + 2) / 2 <= z) ++b;
  while (b * (b + 1) / 2 > z) --b;
  int a = z - b * (b + 1) / 2;  // a <= b
  const int bi = a * 128, bj = b * 128;
  const bool mirror = (a != b);
  const int w = threadIdx.x >> 6, l = threadIdx.x & 63;
  const int lr = l & 15, lk = l >> 4;
  const int ri = w * 32;
  f32x4 acc[2][8] = {};
#pragma unroll
  for (int ks = 0; ks < 4; ++ks) {
    const int k0 = (ks << 5) + (lk << 3);
    bf16x8 ah[2], al[2];
#pragma unroll
    for (int rb = 0; rb < 2; ++rb) {
      size_t off = (size_t)(bi + ri + (rb << 4) + lr) * EMBD + k0;
      ah[rb] = *(const bf16x8*)(Hh + off);
      al[rb] = *(const bf16x8*)(Hl + off);
    }
#pragma unroll
    for (int cb = 0; cb < 8; ++cb) {
      size_t off = (size_t)(bj + (cb << 4) + lr) * EMBD + k0;
      bf16x8 bh = *(const bf16x8*)(Hh + off);
      bf16x8 bl = *(const bf16x8*)(Hl + off);
#pragma unroll
      for (int rb = 0; rb < 2; ++rb) {
        acc[rb][cb] = __builtin_amdgcn_mfma_f32_16x16x32_bf16(ah[rb], bh, acc[rb][cb], 0, 0, 0);
        acc[rb][cb] = __builtin_amdgcn_mfma_f32_16x16x32_bf16(al[rb], bh, acc[rb][cb], 0, 0, 0);
        acc[rb][cb] = __builtin_amdgcn_mfma_f32_16x16x32_bf16(ah[rb], bl, acc[rb][cb], 0, 0, 0);
      }
    }
  }
#pragma unroll
  for (int rb = 0; rb < 2; ++rb)
#pragma unroll
    for (int cb = 0; cb < 8; ++cb) {
      int r0 = ri + (rb << 4) + (lk << 2);
      int c0 = (cb << 4) + lr;
#pragma unroll
      for (int r = 0; r < 4; ++r) {
        float v = acc[rb][cb][r];
        C[(size_t)(bi + r0 + r) * NN + bj + c0] = v;
        if (mirror) sm[r0 + r][c0] = v;
      }
    }
  if (mirror) {
    __syncthreads();
    for (int idx = threadIdx.x; idx < 128 * 128; idx += 256) {
      int jr = idx >> 7, c = idx & 127;
      C[(size_t)(bj + jr) * NN + bi + c] = sm[c][jr];
    }
  }
}

// ---------------- launch ----------------

extern "C" void kernel_launch(void* const* d_in, const int* in_sizes, int n_in,
                              void* d_out, int out_size, void* d_ws, size_t ws_size,
                              hipStream_t stream) {
  const float* x      = (const float*)d_in[0];
  const int*   ei     = (const int*)d_in[1];
  const float* res_W1 = (const float*)d_in[2];
  const float* res_b1 = (const float*)d_in[3];
  const float* res_W2 = (const float*)d_in[4];
  const float* res_b2 = (const float*)d_in[5];
  const float* fc_W1  = (const float*)d_in[6];
  const float* fc_b1  = (const float*)d_in[7];
  const float* fc_W2  = (const float*)d_in[8];
  const float* fc_b2  = (const float*)d_in[9];
  const float* g_W0   = (const float*)d_in[10];
  const float* g_b0   = (const float*)d_in[11];
  const float* g_W1   = (const float*)d_in[12];
  const float* g_b1   = (const float*)d_in[13];
  const float* g_W2   = (const float*)d_in[14];
  const float* g_b2   = (const float*)d_in[15];
  const float* dec_W1 = (const float*)d_in[16];
  const float* dec_b1 = (const float*)d_in[17];
  const float* dec_W2 = (const float*)d_in[18];
  const float* dec_b2 = (const float*)d_in[19];

  float* out   = (float*)d_out;
  float* X_hat = out;                               // [N,F]
  float* A_hat = out + (size_t)NN * FF;             // [N,N]
  float* R     = A_hat + (size_t)NN * NN;           // [N,F]

  char* ws = (char*)d_ws;
  size_t o = 0;
  auto alloc = [&](size_t bytes) -> void* {
    void* p = ws + o;
    o += (bytes + 1023) & ~(size_t)1023;
    return p;
  };
  // ---- fixed region (~4.5 MB) ----
  int* cnt_src = (int*)alloc(NN * 4);   // 4 contiguous counter arrays (one memset)
  int* cnt_dst = (int*)alloc(NN * 4);
  int* cur_src = (int*)alloc(NN * 4);
  int* cur_dst = (int*)alloc(NN * 4);
  int* off_src = (int*)alloc((NN + 1) * 4);
  int* off_dst = (int*)alloc((NN + 1) * 4);
  int* adj_src = (int*)alloc((size_t)EE * 4);
  int* adj_dst = (int*)alloc((size_t)EE * 4);
  float* dinv  = (float*)alloc(NN * 4);
  short* Wt_h  = (short*)alloc(524288 * 2);
  short* Wt_l  = (short*)alloc(524288 * 2);
  // ---- 4 slabs x 8 MB, lifetime-multiplexed (total ws ~36.5 MB) ----
  const size_t SLAB = (size_t)8 * 1024 * 1024;
  char* slabA = (char*)alloc(SLAB);
  char* slabB = (char*)alloc(SLAB);
  char* slabC = (char*)alloc(SLAB);
  char* slabD = (char*)alloc(SLAB);
  // slabA tenants (disjoint lifetimes): S1h -> Xh+Xl -> M1h+M1l -> M2h+M2l -> D1h+D1l
  short* S1h = (short*)slabA;
  short* Xh  = (short*)slabA;            short* Xl  = (short*)(slabA + SLAB / 2);
  short* M1h = (short*)slabA;            short* M1l = (short*)(slabA + SLAB / 2);
  short* M2h = (short*)slabA;            short* M2l = (short*)(slabA + SLAB / 2);
  short* D1h = (short*)slabA;            short* D1l = (short*)(slabA + SLAB / 2);
  // slabB tenants: S1l -> B3f -> B4f -> G2f
  short* S1l = (short*)slabB;
  float* B3f = (float*)slabB;
  float* B4f = (float*)slabB;
  float* G2f = (float*)slabB;
  // slabC tenants: Rh+Rl -> B1f -> G1f
  short* Rh  = (short*)slabC;            short* Rl  = (short*)(slabC + SLAB / 2);
  float* B1f = (float*)slabC;
  float* G1f = (float*)slabC;
  // slabD tenants: B3h+B3l -> Hh+Hl
  short* B3h = (short*)slabD;            short* B3l = (short*)(slabD + SLAB / 2);
  short* Hh  = (short*)slabD;            short* Hl  = (short*)(slabD + (size_t)2 * 1024 * 1024);

  // Wt layout offsets (elements), all stored [N][K]:
  const int o_resW2 = 0;        // [256][512]
  const int o_fcW1  = 131072;   // [256][256]
  const int o_fcW2  = 196608;
  const int o_gW0   = 262144;
  const int o_gW1   = 327680;
  const int o_gW2   = 393216;   // [128][256]
  const int o_decW1 = 425984;   // [256][128]
  const int o_decW2 = 458752;   // [256][256]

  hipMemsetAsync(cnt_src, 0, (size_t)NN * 4 * 4, stream);

  count_kernel<<<EE / 256, 256, 0, stream>>>(ei, cnt_src, cnt_dst);
  scan_kernel<<<2, 1024, 0, stream>>>(cnt_src, cnt_dst, off_src, off_dst);
  fill_kernel<<<EE / 256, 256, 0, stream>>>(ei, off_src, off_dst, cur_src, cur_dst,
                                            adj_src, adj_dst);
  dinv_kernel<<<NN / 256, 256, 0, stream>>>(cnt_dst, dinv);

  WTab tab;
  tab.d[0] = {res_W2, Wt_h + o_resW2, Wt_l + o_resW2, RESH, FF};
  tab.d[1] = {fc_W1,  Wt_h + o_fcW1,  Wt_l + o_fcW1,  FF,   REPH};
  tab.d[2] = {fc_W2,  Wt_h + o_fcW2,  Wt_l + o_fcW2,  REPH, REPH};
  tab.d[3] = {g_W0,   Wt_h + o_gW0,   Wt_l + o_gW0,   FF,   REPH};
  tab.d[4] = {g_W1,   Wt_h + o_gW1,   Wt_l + o_gW1,   REPH, REPH};
  tab.d[5] = {g_W2,   Wt_h + o_gW2,   Wt_l + o_gW2,   REPH, EMBD};
  tab.d[6] = {dec_W1, Wt_h + o_decW1, Wt_l + o_decW1, EMBD, REPH};
  tab.d[7] = {dec_W2, Wt_h + o_decW2, Wt_l + o_decW2, REPH, FF};
  prep_w<<<dim3(128, 8), 256, 0, stream>>>(tab);

  // stage 2: S1 = split(relu(A @ res_W1 + res_b1))  [slabA,slabB]
  s1_kernel<<<NN, 256, 0, stream>>>(res_W1, res_b1, off_src, adj_src, S1h, S1l);
  // stage 3: R = relu(S1 @ res_W2 + res_b2) -> d_out R + [slabC]
  gemmS<8><<<dim3(2, 128), 256, 0, stream>>>(S1h, S1l, Wt_h + o_resW2, Wt_l + o_resW2,
      res_b2, 1, R, Rh, Rl, RESH, FF);
  // stage 4: B3 = relu(R @ fc_W1 + fc_b1) -> [slabB f] + [slabD hi/lo]
  gemmS<8><<<dim3(2, 128), 256, 0, stream>>>(Rh, Rl, Wt_h + o_fcW1, Wt_l + o_fcW1,
      fc_b1, 1, B3f, B3h, B3l, FF, REPH);
  // stage 5: x -> hi/lo  [slabA]
  conv_split<<<(NN * FF) / 1024, 256, 0, stream>>>(x, Xh, Xl);
  // stage 6: B1 = x @ g_W0 -> [slabC f]
  gemmS<8><<<dim3(2, 128), 256, 0, stream>>>(Xh, Xl, Wt_h + o_gW0, Wt_l + o_gW0,
      nullptr, 0, B1f, nullptr, nullptr, FF, REPH);
  // stage 7: M1 = split( relu(agg0(B1) + g_b0) * exp(-g*B3) )  [slabA]
  agg0_fused<<<NN, REPH, 0, stream>>>(B1f, g_b0, B3f, off_dst, adj_dst, M1h, M1l);
  // stage 8: G1 = M1 @ g_W1 -> [slabC f]
  gemmS<8><<<dim3(2, 128), 256, 0, stream>>>(M1h, M1l, Wt_h + o_gW1, Wt_l + o_gW1,
      nullptr, 0, G1f, nullptr, nullptr, REPH, REPH);
  // stage 9: B4 = relu(B3 @ fc_W2 + fc_b2) -> [slabB f]
  gemmS<8><<<dim3(2, 128), 256, 0, stream>>>(B3h, B3l, Wt_h + o_fcW2, Wt_l + o_fcW2,
      fc_b2, 1, B4f, nullptr, nullptr, REPH, REPH);
  // stage 10: M2 = split( relu(aggn(G1) + g_b1) * exp(-g*B4) )  [slabA]
  aggn_fused<<<NN, REPH, 0, stream>>>(G1f, g_b1, dinv, B4f, off_dst, adj_dst,
                                      M2h, M2l, REPH);
  // stage 11: G2 = M2 @ g_W2 -> [slabB f]  [N, EMBD]
  gemmS<4><<<dim3(2, 128), 256, 0, stream>>>(M2h, M2l, Wt_h + o_gW2, Wt_l + o_gW2,
      nullptr, 0, G2f, nullptr, nullptr, REPH, EMBD);
  // stage 12: H = split( relu(aggn(G2) + g_b2) )  [slabD]
  aggn_fused<<<NN, EMBD, 0, stream>>>(G2f, g_b2, dinv, nullptr, off_dst, adj_dst,
                                      Hh, Hl, EMBD);
  // stage 13: D1 = relu(H @ dec_W1 + dec_b1) -> [slabA hi/lo]
  gemmS<8><<<dim3(2, 128), 256, 0, stream>>>(Hh, Hl, Wt_h + o_decW1, Wt_l + o_decW1,
      dec_b1, 1, nullptr, D1h, D1l, EMBD, REPH);
  // stage 14: X_hat = relu(D1 @ dec_W2 + dec_b2) -> d_out
  gemmS<8><<<dim3(2, 128), 256, 0, stream>>>(D1h, D1l, Wt_h + o_decW2, Wt_l + o_decW2,
      dec_b2, 1, X_hat, nullptr, nullptr, REPH, FF);
  // stage 15: A_hat = H @ H^T (symmetric)
  ahat_sym<<<2080, 256, 0, stream>>>(Hh, Hl, A_hat);
}

// Round 5
// 787.471 us; speedup vs baseline: 1.1958x; 1.0162x over previous
//
#include <hip/hip_runtime.h>
#include <cstddef>
#include <cstdint>
#include <math.h>

#define NN   8192
#define FF   256
#define RESH 512
#define REPH 256
#define EMBD 128
#define EE   262144
#define GAMMA_ 0.1f

typedef __attribute__((ext_vector_type(8))) short bf16x8;
typedef __attribute__((ext_vector_type(4))) float f32x4;
typedef __attribute__((ext_vector_type(2))) float f32x2;
typedef __attribute__((ext_vector_type(4))) short s16x4;
typedef __attribute__((ext_vector_type(2))) short s16x2;

// split fp32 -> hi/lo bf16 (RTNE both): x ~= hi + lo with rel err ~2^-17
__device__ inline void f2hilo(float x, short& h, short& l) {
  unsigned u = __float_as_uint(x);
  unsigned r = u + 0x7FFFu + ((u >> 16) & 1u);
  h = (short)(r >> 16);
  float hf = __uint_as_float(r & 0xFFFF0000u);
  float lf = x - hf;
  unsigned u2 = __float_as_uint(lf);
  unsigned r2 = u2 + 0x7FFFu + ((u2 >> 16) & 1u);
  l = (short)(r2 >> 16);
}

// ---------------- CSR construction ----------------

__global__ void count_kernel(const int* __restrict__ ei, int* __restrict__ cnt_src,
                             int* __restrict__ cnt_dst) {
  int e = blockIdx.x * blockDim.x + threadIdx.x;
  if (e < EE) {
    atomicAdd(&cnt_src[ei[e]], 1);
    atomicAdd(&cnt_dst[ei[EE + e]], 1);
  }
}

// block 0: scan cnt_src -> off_src; block 1: scan cnt_dst -> off_dst (+ dinv)
__global__ void scan_kernel(const int* __restrict__ cnt_src, const int* __restrict__ cnt_dst,
                            int* __restrict__ off_src, int* __restrict__ off_dst,
                            float* __restrict__ dinv) {
  const int* cnt = blockIdx.x ? cnt_dst : cnt_src;
  int* off = blockIdx.x ? off_dst : off_src;
  __shared__ int sm[1024];
  int carry = 0;
  for (int ch = 0; ch < NN / 1024; ++ch) {
    int idx = ch * 1024 + threadIdx.x;
    int v = cnt[idx];
    if (blockIdx.x) dinv[idx] = rsqrtf((float)v + 1.0f);
    int x = v;
    sm[threadIdx.x] = x;
    __syncthreads();
    for (int ofs = 1; ofs < 1024; ofs <<= 1) {
      int y = (threadIdx.x >= ofs) ? sm[threadIdx.x - ofs] : 0;
      __syncthreads();
      x += y;
      sm[threadIdx.x] = x;
      __syncthreads();
    }
    off[idx] = x - v + carry;
    carry += sm[1023];
    __syncthreads();
  }
  if (threadIdx.x == 0) off[NN] = carry;
}

__global__ void fill_kernel(const int* __restrict__ ei, const int* __restrict__ off_src,
                            const int* __restrict__ off_dst, int* __restrict__ cur_src,
                            int* __restrict__ cur_dst, int* __restrict__ adj_src,
                            int* __restrict__ adj_dst) {
  int e = blockIdx.x * blockDim.x + threadIdx.x;
  if (e < EE) {
    int s = ei[e], d = ei[EE + e];
    int ps = atomicAdd(&cur_src[s], 1);
    adj_src[off_src[s] + ps] = d;
    int pd = atomicAdd(&cur_dst[d], 1);
    adj_dst[off_dst[d] + pd] = s;
  }
}

// ---------------- sparse A @ res_W1, relu, split (wave-per-half-row float4) ----------------
// waves: half = w&1 -> col half [0,256)/[256,512); par = w>>1 -> neighbor parity.
__global__ __launch_bounds__(256) void s1_v2(const float* __restrict__ W1,
    const float* __restrict__ b1, const int* __restrict__ off_src,
    const int* __restrict__ adj_src, short* __restrict__ S1h, short* __restrict__ S1l) {
  __shared__ f32x4 p2[2][64];
  const int i = blockIdx.x, w = threadIdx.x >> 6, lane = threadIdx.x & 63;
  const int half = w & 1, par = w >> 1;
  const int col = half * 256 + lane * 4;
  const float* base = W1 + col;
  const int beg = off_src[i], end = off_src[i + 1];
  f32x4 acc = {};
  int k = beg + par;
  for (; k + 6 < end; k += 8) {
    int s0 = adj_src[k], s1 = adj_src[k + 2], s2 = adj_src[k + 4], s3 = adj_src[k + 6];
    f32x4 h0 = *(const f32x4*)(base + (size_t)s0 * RESH);
    f32x4 h1 = *(const f32x4*)(base + (size_t)s1 * RESH);
    f32x4 h2 = *(const f32x4*)(base + (size_t)s2 * RESH);
    f32x4 h3 = *(const f32x4*)(base + (size_t)s3 * RESH);
    acc += h0 + h1 + h2 + h3;
  }
  for (; k < end; k += 2) {
    int s = adj_src[k];
    acc += *(const f32x4*)(base + (size_t)s * RESH);
  }
  if (par == 1) p2[half][lane] = acc;
  __syncthreads();
  if (par == 0) {
    acc += p2[half][lane];
    f32x4 bb = *(const f32x4*)(b1 + col);
    s16x4 vh, vl;
#pragma unroll
    for (int j = 0; j < 4; ++j) {
      float v = fmaxf(acc[j] + bb[j], 0.f);
      short hh, ll;
      f2hilo(v, hh, ll);
      vh[j] = hh; vl[j] = ll;
    }
    size_t o = (size_t)i * RESH + col;
    *(s16x4*)(S1h + o) = vh;
    *(s16x4*)(S1l + o) = vl;
  }
}

// ---------------- agg layer0 (no norm) + bias/relu/mod/split; C=256, wave-per-row -------
__global__ __launch_bounds__(256) void agg0_v2(const float* __restrict__ h,
    const float* __restrict__ b, const float* __restrict__ mod,
    const int* __restrict__ off_dst, const int* __restrict__ adj_dst,
    short* __restrict__ oh, short* __restrict__ ol) {
  __shared__ f32x4 part[3][64];
  const int d = blockIdx.x, w = threadIdx.x >> 6, lane = threadIdx.x & 63;
  const float* base = h + lane * 4;
  const int beg = off_dst[d], end = off_dst[d + 1];
  f32x4 acc = {};
  int k = beg + w;
  for (; k + 12 < end; k += 16) {
    int s0 = adj_dst[k], s1 = adj_dst[k + 4], s2 = adj_dst[k + 8], s3 = adj_dst[k + 12];
    f32x4 h0 = *(const f32x4*)(base + (size_t)s0 * REPH);
    f32x4 h1 = *(const f32x4*)(base + (size_t)s1 * REPH);
    f32x4 h2 = *(const f32x4*)(base + (size_t)s2 * REPH);
    f32x4 h3 = *(const f32x4*)(base + (size_t)s3 * REPH);
    acc += h0 + h1 + h2 + h3;
  }
  for (; k < end; k += 4) {
    int s = adj_dst[k];
    acc += *(const f32x4*)(base + (size_t)s * REPH);
  }
  if (w) part[w - 1][lane] = acc;
  __syncthreads();
  if (w == 0) {
    acc += part[0][lane] + part[1][lane] + part[2][lane];
    size_t o = (size_t)d * REPH + lane * 4;
    f32x4 bb = *(const f32x4*)(b + lane * 4);
    f32x4 mm = *(const f32x4*)(mod + o);
    s16x4 vh, vl;
#pragma unroll
    for (int j = 0; j < 4; ++j) {
      float v = fmaxf(acc[j] + bb[j], 0.f) * expf(-GAMMA_ * mm[j]);
      short hh, ll;
      f2hilo(v, hh, ll);
      vh[j] = hh; vl[j] = ll;
    }
    *(s16x4*)(oh + o) = vh;
    *(s16x4*)(ol + o) = vl;
  }
}

// ---------------- normalized agg + bias/relu/[mod]/split; C=256 ----------------
__global__ __launch_bounds__(256) void aggn256_v2(const float* __restrict__ h,
    const float* __restrict__ b, const float* __restrict__ dinv,
    const float* __restrict__ mod, const int* __restrict__ off_dst,
    const int* __restrict__ adj_dst, short* __restrict__ oh, short* __restrict__ ol) {
  __shared__ f32x4 part[3][64];
  const int d = blockIdx.x, w = threadIdx.x >> 6, lane = threadIdx.x & 63;
  const float* base = h + lane * 4;
  const int beg = off_dst[d], end = off_dst[d + 1];
  f32x4 acc = {};
  int k = beg + w;
  for (; k + 12 < end; k += 16) {
    int s0 = adj_dst[k], s1 = adj_dst[k + 4], s2 = adj_dst[k + 8], s3 = adj_dst[k + 12];
    float d0 = dinv[s0], d1 = dinv[s1], d2 = dinv[s2], d3 = dinv[s3];
    f32x4 h0 = *(const f32x4*)(base + (size_t)s0 * REPH);
    f32x4 h1 = *(const f32x4*)(base + (size_t)s1 * REPH);
    f32x4 h2 = *(const f32x4*)(base + (size_t)s2 * REPH);
    f32x4 h3 = *(const f32x4*)(base + (size_t)s3 * REPH);
    acc += h0 * d0 + h1 * d1 + h2 * d2 + h3 * d3;
  }
  for (; k < end; k += 4) {
    int s = adj_dst[k];
    acc += *(const f32x4*)(base + (size_t)s * REPH) * dinv[s];
  }
  if (w) part[w - 1][lane] = acc;
  __syncthreads();
  if (w == 0) {
    acc += part[0][lane] + part[1][lane] + part[2][lane];
    const float dd = dinv[d];
    size_t o = (size_t)d * REPH + lane * 4;
    f32x4 bb = *(const f32x4*)(b + lane * 4);
    f32x4 self = *(const f32x4*)(h + o);
    s16x4 vh, vl;
    if (mod) {
      f32x4 mm = *(const f32x4*)(mod + o);
#pragma unroll
      for (int j = 0; j < 4; ++j) {
        float v = fmaxf(acc[j] * dd + self[j] * dd * dd + bb[j], 0.f) * expf(-GAMMA_ * mm[j]);
        short hh, ll; f2hilo(v, hh, ll); vh[j] = hh; vl[j] = ll;
      }
    } else {
#pragma unroll
      for (int j = 0; j < 4; ++j) {
        float v = fmaxf(acc[j] * dd + self[j] * dd * dd + bb[j], 0.f);
        short hh, ll; f2hilo(v, hh, ll); vh[j] = hh; vl[j] = ll;
      }
    }
    *(s16x4*)(oh + o) = vh;
    *(s16x4*)(ol + o) = vl;
  }
}

// ---------------- normalized agg + bias/relu/split; C=128 (float2 lanes) ----------------
__global__ __launch_bounds__(256) void aggn128_v2(const float* __restrict__ h,
    const float* __restrict__ b, const float* __restrict__ dinv,
    const int* __restrict__ off_dst, const int* __restrict__ adj_dst,
    short* __restrict__ oh, short* __restrict__ ol) {
  __shared__ f32x2 part[3][64];
  const int d = blockIdx.x, w = threadIdx.x >> 6, lane = threadIdx.x & 63;
  const float* base = h + lane * 2;
  const int beg = off_dst[d], end = off_dst[d + 1];
  f32x2 acc = {};
  int k = beg + w;
  for (; k + 12 < end; k += 16) {
    int s0 = adj_dst[k], s1 = adj_dst[k + 4], s2 = adj_dst[k + 8], s3 = adj_dst[k + 12];
    float d0 = dinv[s0], d1 = dinv[s1], d2 = dinv[s2], d3 = dinv[s3];
    f32x2 h0 = *(const f32x2*)(base + (size_t)s0 * EMBD);
    f32x2 h1 = *(const f32x2*)(base + (size_t)s1 * EMBD);
    f32x2 h2 = *(const f32x2*)(base + (size_t)s2 * EMBD);
    f32x2 h3 = *(const f32x2*)(base + (size_t)s3 * EMBD);
    acc += h0 * d0 + h1 * d1 + h2 * d2 + h3 * d3;
  }
  for (; k < end; k += 4) {
    int s = adj_dst[k];
    acc += *(const f32x2*)(base + (size_t)s * EMBD) * dinv[s];
  }
  if (w) part[w - 1][lane] = acc;
  __syncthreads();
  if (w == 0) {
    acc += part[0][lane] + part[1][lane] + part[2][lane];
    const float dd = dinv[d];
    size_t o = (size_t)d * EMBD + lane * 2;
    f32x2 bb = *(const f32x2*)(b + lane * 2);
    f32x2 self = *(const f32x2*)(h + o);
    s16x2 vh, vl;
#pragma unroll
    for (int j = 0; j < 2; ++j) {
      float v = fmaxf(acc[j] * dd + self[j] * dd * dd + bb[j], 0.f);
      short hh, ll; f2hilo(v, hh, ll); vh[j] = hh; vl[j] = ll;
    }
    *(s16x2*)(oh + o) = vh;
    *(s16x2*)(ol + o) = vl;
  }
}

// ---------------- weight prep: W [K][N] fp32 -> hi/lo bf16 [N][K] ----------------
struct WDesc { const float* src; short* h; short* l; int K; int N; };
struct WTab { WDesc d[8]; };

__global__ void prep_w(WTab tab) {
  WDesc d = tab.d[blockIdx.y];
  int total = d.K * d.N;
  for (int i = blockIdx.x * 256 + threadIdx.x; i < total; i += 128 * 256) {
    int n = i / d.K, k = i - n * d.K;
    float x = d.src[(size_t)k * d.N + n];
    short hh, ll;
    f2hilo(x, hh, ll);
    d.h[i] = hh;
    d.l[i] = ll;
  }
}

// ---------------- fp32 -> hi/lo planes (vectorized), n % 1024 == 0 ----------------
__global__ void conv_split(const float* __restrict__ in, short* __restrict__ oh,
                           short* __restrict__ ol) {
  int i = (blockIdx.x * 256 + threadIdx.x) * 4;
  f32x4 v = *(const f32x4*)(in + i);
  s16x4 vh, vl;
#pragma unroll
  for (int j = 0; j < 4; ++j) {
    short hh, ll;
    f2hilo(v[j], hh, ll);
    vh[j] = hh;
    vl[j] = ll;
  }
  *(s16x4*)(oh + i) = vh;
  *(s16x4*)(ol + i) = vl;
}

// ---------------- split-bf16 MFMA GEMM, pre-split A and W planes ----------------
template<int CB>
__global__ __launch_bounds__(256) void gemmS(const short* __restrict__ Ah,
    const short* __restrict__ Al, const short* __restrict__ Wh,
    const short* __restrict__ Wl, const float* __restrict__ bias, int doRelu,
    float* __restrict__ outF, short* __restrict__ outH, short* __restrict__ outL,
    int K, int Nc) {
  const int w = threadIdx.x >> 6, l = threadIdx.x & 63;
  const int lr = l & 15, lk = l >> 4;
  const int m0 = blockIdx.y * 64 + w * 16;
  const int n0 = blockIdx.x * (CB * 16);
  f32x4 acc[CB] = {};
  const int nks = K >> 5;
  for (int ks = 0; ks < nks; ++ks) {
    const int k0 = (ks << 5) + (lk << 3);
    size_t aoff = (size_t)(m0 + lr) * K + k0;
    bf16x8 ah = *(const bf16x8*)(Ah + aoff);
    bf16x8 al = *(const bf16x8*)(Al + aoff);
#pragma unroll
    for (int cb = 0; cb < CB; ++cb) {
      size_t boff = (size_t)(n0 + (cb << 4) + lr) * K + k0;
      bf16x8 bh = *(const bf16x8*)(Wh + boff);
      bf16x8 bl = *(const bf16x8*)(Wl + boff);
      acc[cb] = __builtin_amdgcn_mfma_f32_16x16x32_bf16(ah, bh, acc[cb], 0, 0, 0);
      acc[cb] = __builtin_amdgcn_mfma_f32_16x16x32_bf16(al, bh, acc[cb], 0, 0, 0);
      acc[cb] = __builtin_amdgcn_mfma_f32_16x16x32_bf16(ah, bl, acc[cb], 0, 0, 0);
    }
  }
#pragma unroll
  for (int cb = 0; cb < CB; ++cb) {
    int col = n0 + (cb << 4) + lr;
    float bv = bias ? bias[col] : 0.f;
#pragma unroll
    for (int r = 0; r < 4; ++r) {
      int row = m0 + (lk << 2) + r;
      float v = acc[cb][r] + bv;
      if (doRelu) v = fmaxf(v, 0.f);
      size_t off = (size_t)row * Nc + col;
      if (outF) outF[off] = v;
      if (outH) {
        short hh, ll;
        f2hilo(v, hh, ll);
        outH[off] = hh;
        outL[off] = ll;
      }
    }
  }
}

// ---------------- A_hat = H @ H^T (symmetric: upper-tri tiles + LDS-transposed mirror) ----
__global__ __launch_bounds__(256) void ahat_sym(const short* __restrict__ Hh,
    const short* __restrict__ Hl, float* __restrict__ C) {
  __shared__ float sm[128][129];
  int z = blockIdx.x;
  int b = (int)((sqrtf(8.f * (float)z + 1.f) - 1.f) * 0.5f);
  while ((b + 1) * (b + 2) / 2 <= z) ++b;
  while (b * (b + 1) / 2 > z) --b;
  int a = z - b * (b + 1) / 2;  // a <= b
  const int bi = a * 128, bj = b * 128;
  const bool mirror = (a != b);
  const int w = threadIdx.x >> 6, l = threadIdx.x & 63;
  const int lr = l & 15, lk = l >> 4;
  const int ri = w * 32;
  f32x4 acc[2][8] = {};
#pragma unroll
  for (int ks = 0; ks < 4; ++ks) {
    const int k0 = (ks << 5) + (lk << 3);
    bf16x8 ah[2], al[2];
#pragma unroll
    for (int rb = 0; rb < 2; ++rb) {
      size_t off = (size_t)(bi + ri + (rb << 4) + lr) * EMBD + k0;
      ah[rb] = *(const bf16x8*)(Hh + off);
      al[rb] = *(const bf16x8*)(Hl + off);
    }
#pragma unroll
    for (int cb = 0; cb < 8; ++cb) {
      size_t off = (size_t)(bj + (cb << 4) + lr) * EMBD + k0;
      bf16x8 bh = *(const bf16x8*)(Hh + off);
      bf16x8 bl = *(const bf16x8*)(Hl + off);
#pragma unroll
      for (int rb = 0; rb < 2; ++rb) {
        acc[rb][cb] = __builtin_amdgcn_mfma_f32_16x16x32_bf16(ah[rb], bh, acc[rb][cb], 0, 0, 0);
        acc[rb][cb] = __builtin_amdgcn_mfma_f32_16x16x32_bf16(al[rb], bh, acc[rb][cb], 0, 0, 0);
        acc[rb][cb] = __builtin_amdgcn_mfma_f32_16x16x32_bf16(ah[rb], bl, acc[rb][cb], 0, 0, 0);
      }
    }
  }
#pragma unroll
  for (int rb = 0; rb < 2; ++rb)
#pragma unroll
    for (int cb = 0; cb < 8; ++cb) {
      int r0 = ri + (rb << 4) + (lk << 2);
      int c0 = (cb << 4) + lr;
#pragma unroll
      for (int r = 0; r < 4; ++r) {
        float v = acc[rb][cb][r];
        C[(size_t)(bi + r0 + r) * NN + bj + c0] = v;
        if (mirror) sm[r0 + r][c0] = v;
      }
    }
  if (mirror) {
    __syncthreads();
    for (int idx = threadIdx.x; idx < 128 * 128; idx += 256) {
      int jr = idx >> 7, c = idx & 127;
      C[(size_t)(bj + jr) * NN + bi + c] = sm[c][jr];
    }
  }
}

// ---------------- launch ----------------

extern "C" void kernel_launch(void* const* d_in, const int* in_sizes, int n_in,
                              void* d_out, int out_size, void* d_ws, size_t ws_size,
                              hipStream_t stream) {
  const float* x      = (const float*)d_in[0];
  const int*   ei     = (const int*)d_in[1];
  const float* res_W1 = (const float*)d_in[2];
  const float* res_b1 = (const float*)d_in[3];
  const float* res_W2 = (const float*)d_in[4];
  const float* res_b2 = (const float*)d_in[5];
  const float* fc_W1  = (const float*)d_in[6];
  const float* fc_b1  = (const float*)d_in[7];
  const float* fc_W2  = (const float*)d_in[8];
  const float* fc_b2  = (const float*)d_in[9];
  const float* g_W0   = (const float*)d_in[10];
  const float* g_b0   = (const float*)d_in[11];
  const float* g_W1   = (const float*)d_in[12];
  const float* g_b1   = (const float*)d_in[13];
  const float* g_W2   = (const float*)d_in[14];
  const float* g_b2   = (const float*)d_in[15];
  const float* dec_W1 = (const float*)d_in[16];
  const float* dec_b1 = (const float*)d_in[17];
  const float* dec_W2 = (const float*)d_in[18];
  const float* dec_b2 = (const float*)d_in[19];

  float* out   = (float*)d_out;
  float* X_hat = out;                               // [N,F]
  float* A_hat = out + (size_t)NN * FF;             // [N,N]
  float* R     = A_hat + (size_t)NN * NN;           // [N,F]

  char* ws = (char*)d_ws;
  size_t o = 0;
  auto alloc = [&](size_t bytes) -> void* {
    void* p = ws + o;
    o += (bytes + 1023) & ~(size_t)1023;
    return p;
  };
  // ---- fixed region (~4.5 MB) ----
  int* cnt_src = (int*)alloc(NN * 4);   // 4 contiguous counter arrays (one memset)
  int* cnt_dst = (int*)alloc(NN * 4);
  int* cur_src = (int*)alloc(NN * 4);
  int* cur_dst = (int*)alloc(NN * 4);
  int* off_src = (int*)alloc((NN + 1) * 4);
  int* off_dst = (int*)alloc((NN + 1) * 4);
  int* adj_src = (int*)alloc((size_t)EE * 4);
  int* adj_dst = (int*)alloc((size_t)EE * 4);
  float* dinv  = (float*)alloc(NN * 4);
  short* Wt_h  = (short*)alloc(524288 * 2);
  short* Wt_l  = (short*)alloc(524288 * 2);
  // ---- 4 slabs x 8 MB, lifetime-multiplexed (total ws ~36.5 MB) ----
  const size_t SLAB = (size_t)8 * 1024 * 1024;
  char* slabA = (char*)alloc(SLAB);
  char* slabB = (char*)alloc(SLAB);
  char* slabC = (char*)alloc(SLAB);
  char* slabD = (char*)alloc(SLAB);
  // slabA tenants: S1h -> Xh+Xl -> M1h+M1l -> M2h+M2l -> D1h+D1l
  short* S1h = (short*)slabA;
  short* Xh  = (short*)slabA;            short* Xl  = (short*)(slabA + SLAB / 2);
  short* M1h = (short*)slabA;            short* M1l = (short*)(slabA + SLAB / 2);
  short* M2h = (short*)slabA;            short* M2l = (short*)(slabA + SLAB / 2);
  short* D1h = (short*)slabA;            short* D1l = (short*)(slabA + SLAB / 2);
  // slabB tenants: S1l -> B3f -> B4f -> G2f
  short* S1l = (short*)slabB;
  float* B3f = (float*)slabB;
  float* B4f = (float*)slabB;
  float* G2f = (float*)slabB;
  // slabC tenants: Rh+Rl -> B1f -> G1f
  short* Rh  = (short*)slabC;            short* Rl  = (short*)(slabC + SLAB / 2);
  float* B1f = (float*)slabC;
  float* G1f = (float*)slabC;
  // slabD tenants: B3h+B3l -> Hh+Hl
  short* B3h = (short*)slabD;            short* B3l = (short*)(slabD + SLAB / 2);
  short* Hh  = (short*)slabD;            short* Hl  = (short*)(slabD + (size_t)2 * 1024 * 1024);

  // Wt layout offsets (elements), all stored [N][K]:
  const int o_resW2 = 0;        // [256][512]
  const int o_fcW1  = 131072;   // [256][256]
  const int o_fcW2  = 196608;
  const int o_gW0   = 262144;
  const int o_gW1   = 327680;
  const int o_gW2   = 393216;   // [128][256]
  const int o_decW1 = 425984;   // [256][128]
  const int o_decW2 = 458752;   // [256][256]

  hipMemsetAsync(cnt_src, 0, (size_t)NN * 4 * 4, stream);

  count_kernel<<<EE / 256, 256, 0, stream>>>(ei, cnt_src, cnt_dst);
  scan_kernel<<<2, 1024, 0, stream>>>(cnt_src, cnt_dst, off_src, off_dst, dinv);
  fill_kernel<<<EE / 256, 256, 0, stream>>>(ei, off_src, off_dst, cur_src, cur_dst,
                                            adj_src, adj_dst);

  WTab tab;
  tab.d[0] = {res_W2, Wt_h + o_resW2, Wt_l + o_resW2, RESH, FF};
  tab.d[1] = {fc_W1,  Wt_h + o_fcW1,  Wt_l + o_fcW1,  FF,   REPH};
  tab.d[2] = {fc_W2,  Wt_h + o_fcW2,  Wt_l + o_fcW2,  REPH, REPH};
  tab.d[3] = {g_W0,   Wt_h + o_gW0,   Wt_l + o_gW0,   FF,   REPH};
  tab.d[4] = {g_W1,   Wt_h + o_gW1,   Wt_l + o_gW1,   REPH, REPH};
  tab.d[5] = {g_W2,   Wt_h + o_gW2,   Wt_l + o_gW2,   REPH, EMBD};
  tab.d[6] = {dec_W1, Wt_h + o_decW1, Wt_l + o_decW1, EMBD, REPH};
  tab.d[7] = {dec_W2, Wt_h + o_decW2, Wt_l + o_decW2, REPH, FF};
  prep_w<<<dim3(128, 8), 256, 0, stream>>>(tab);

  // S1 = split(relu(A @ res_W1 + res_b1))  [slabA,slabB]
  s1_v2<<<NN, 256, 0, stream>>>(res_W1, res_b1, off_src, adj_src, S1h, S1l);
  // R = relu(S1 @ res_W2 + res_b2) -> d_out R + [slabC]
  gemmS<8><<<dim3(2, 128), 256, 0, stream>>>(S1h, S1l, Wt_h + o_resW2, Wt_l + o_resW2,
      res_b2, 1, R, Rh, Rl, RESH, FF);
  // B3 = relu(R @ fc_W1 + fc_b1) -> [slabB f] + [slabD hi/lo]
  gemmS<8><<<dim3(2, 128), 256, 0, stream>>>(Rh, Rl, Wt_h + o_fcW1, Wt_l + o_fcW1,
      fc_b1, 1, B3f, B3h, B3l, FF, REPH);
  // x -> hi/lo  [slabA]
  conv_split<<<(NN * FF) / 1024, 256, 0, stream>>>(x, Xh, Xl);
  // B1 = x @ g_W0 -> [slabC f]
  gemmS<8><<<dim3(2, 128), 256, 0, stream>>>(Xh, Xl, Wt_h + o_gW0, Wt_l + o_gW0,
      nullptr, 0, B1f, nullptr, nullptr, FF, REPH);
  // M1 = split( relu(agg0(B1) + g_b0) * exp(-g*B3) )  [slabA]
  agg0_v2<<<NN, 256, 0, stream>>>(B1f, g_b0, B3f, off_dst, adj_dst, M1h, M1l);
  // G1 = M1 @ g_W1 -> [slabC f]
  gemmS<8><<<dim3(2, 128), 256, 0, stream>>>(M1h, M1l, Wt_h + o_gW1, Wt_l + o_gW1,
      nullptr, 0, G1f, nullptr, nullptr, REPH, REPH);
  // B4 = relu(B3 @ fc_W2 + fc_b2) -> [slabB f]
  gemmS<8><<<dim3(2, 128), 256, 0, stream>>>(B3h, B3l, Wt_h + o_fcW2, Wt_l + o_fcW2,
      fc_b2, 1, B4f, nullptr, nullptr, REPH, REPH);
  // M2 = split( relu(aggn(G1) + g_b1) * exp(-g*B4) )  [slabA]
  aggn256_v2<<<NN, 256, 0, stream>>>(G1f, g_b1, dinv, B4f, off_dst, adj_dst, M2h, M2l);
  // G2 = M2 @ g_W2 -> [slabB f]  [N, EMBD]
  gemmS<4><<<dim3(2, 128), 256, 0, stream>>>(M2h, M2l, Wt_h + o_gW2, Wt_l + o_gW2,
      nullptr, 0, G2f, nullptr, nullptr, REPH, EMBD);
  // H = split( relu(aggn(G2) + g_b2) )  [slabD]
  aggn128_v2<<<NN, 256, 0, stream>>>(G2f, g_b2, dinv, off_dst, adj_dst, Hh, Hl);
  // D1 = relu(H @ dec_W1 + dec_b1) -> [slabA hi/lo]
  gemmS<8><<<dim3(2, 128), 256, 0, stream>>>(Hh, Hl, Wt_h + o_decW1, Wt_l + o_decW1,
      dec_b1, 1, nullptr, D1h, D1l, EMBD, REPH);
  // X_hat = relu(D1 @ dec_W2 + dec_b2) -> d_out
  gemmS<8><<<dim3(2, 128), 256, 0, stream>>>(D1h, D1l, Wt_h + o_decW2, Wt_l + o_decW2,
      dec_b2, 1, X_hat, nullptr, nullptr, REPH, FF);
  // A_hat = H @ H^T (symmetric)
  ahat_sym<<<2080, 256, 0, stream>>>(Hh, Hl, A_hat);
}